// Round 2
// baseline (1203.310 us; speedup 1.0000x reference)
//
#include <hip/hip_runtime.h>
#include <hip/hip_bf16.h>
#include <math.h>

// Problem constants
#define BB 4
#define TT 1024
#define DIM 1024
#define HEADS 16
#define DH 64
#define INNER 1024
#define MLP 4096

// mod chunk offsets (per batch row of 6*DIM)
#define OFF_SH_MSA 0
#define OFF_SC_MSA 1024
#define OFF_G_MSA  2048
#define OFF_SH_MLP 3072
#define OFF_SC_MLP 4096
#define OFF_G_MLP  5120

typedef __attribute__((ext_vector_type(8))) short bf16x8;   // 8 bf16 in 4 VGPRs
typedef __attribute__((ext_vector_type(4))) float fx4;      // MFMA accumulator

__device__ __forceinline__ unsigned short f2bf(float f) {
    __hip_bfloat16 h = __float2bfloat16(f);   // RNE
    return __builtin_bit_cast(unsigned short, h);
}
__device__ __forceinline__ float bflo(unsigned u) { return __uint_as_float(u << 16); }
__device__ __forceinline__ float bfhi(unsigned u) { return __uint_as_float(u & 0xffff0000u); }

__device__ __forceinline__ void gload_lds16(const void* g, void* l) {
    __builtin_amdgcn_global_load_lds((const __attribute__((address_space(1))) void*)g,
                                     (__attribute__((address_space(3))) void*)l, 16, 0, 0);
}

// ---------------------------------------------------------------------------
// Kernel 1: mod = silu(c) @ W_mod + b_mod      [B, 6144]  (fp32, tiny)
// ---------------------------------------------------------------------------
__global__ __launch_bounds__(256) void mod_kernel(
    const float* __restrict__ c, const float* __restrict__ W_mod,
    const float* __restrict__ b_mod, float* __restrict__ mod)
{
    __shared__ float sc[BB][1024];
    int tid = threadIdx.x;
    for (int i = tid; i < BB * 1024; i += 256) {
        float v = c[i];
        sc[i >> 10][i & 1023] = v / (1.0f + __expf(-v));
    }
    __syncthreads();
    int n = blockIdx.x * 256 + tid;   // 0..6143
    float a0 = 0.f, a1 = 0.f, a2 = 0.f, a3 = 0.f;
    for (int k = 0; k < 1024; k++) {
        float w = W_mod[(size_t)k * 6144 + n];
        a0 += sc[0][k] * w;
        a1 += sc[1][k] * w;
        a2 += sc[2][k] * w;
        a3 += sc[3][k] * w;
    }
    float bb = b_mod[n];
    mod[0 * 6144 + n] = a0 + bb;
    mod[1 * 6144 + n] = a1 + bb;
    mod[2 * 6144 + n] = a2 + bb;
    mod[3 * 6144 + n] = a3 + bb;
}

// ---------------------------------------------------------------------------
// Kernel 2: fused LayerNorm (affine-free) + modulate -> bf16
// ---------------------------------------------------------------------------
__global__ __launch_bounds__(256) void ln_mod_kernel(
    const float* __restrict__ x, const float* __restrict__ mod,
    int sh_off, int sc_off, unsigned short* __restrict__ out)
{
    int row = blockIdx.x;           // 0..B*T-1
    int b = row >> 10;              // T = 1024
    const float* xr = x + (size_t)row * DIM;
    float4 v = ((const float4*)xr)[threadIdx.x];

    float s1 = v.x + v.y + v.z + v.w;
    float s2 = v.x * v.x + v.y * v.y + v.z * v.z + v.w * v.w;
    #pragma unroll
    for (int off = 32; off > 0; off >>= 1) {
        s1 += __shfl_down(s1, off, 64);
        s2 += __shfl_down(s2, off, 64);
    }
    __shared__ float red[8];
    int lane = threadIdx.x & 63, w = threadIdx.x >> 6;
    if (lane == 0) { red[w] = s1; red[4 + w] = s2; }
    __syncthreads();
    s1 = red[0] + red[1] + red[2] + red[3];
    s2 = red[4] + red[5] + red[6] + red[7];
    float mu = s1 * (1.0f / DIM);
    float var = s2 * (1.0f / DIM) - mu * mu;
    float rs = rsqrtf(var + 1e-5f);

    int col = threadIdx.x * 4;
    const float* mb = mod + (size_t)b * 6144;
    float4 sc4 = *(const float4*)(mb + sc_off + col);
    float4 sh4 = *(const float4*)(mb + sh_off + col);
    ushort4 o;
    o.x = f2bf((v.x - mu) * rs * (1.0f + sc4.x) + sh4.x);
    o.y = f2bf((v.y - mu) * rs * (1.0f + sc4.y) + sh4.y);
    o.z = f2bf((v.z - mu) * rs * (1.0f + sc4.z) + sh4.z);
    o.w = f2bf((v.w - mu) * rs * (1.0f + sc4.w) + sh4.w);
    ((ushort4*)(out + (size_t)row * DIM))[threadIdx.x] = o;
}

// ---------------------------------------------------------------------------
// Kernel 3: weight transpose+convert: W [K,N] fp32 -> Wt [N,K] bf16
// grid (N/32, K/32), 256 threads
// ---------------------------------------------------------------------------
__global__ __launch_bounds__(256) void wcvt_kernel(
    const float* __restrict__ W, unsigned short* __restrict__ Wt, int K, int N)
{
    __shared__ float tile[32][33];
    int n0 = blockIdx.x * 32, k0 = blockIdx.y * 32;
    int tx = threadIdx.x & 31, ty = threadIdx.x >> 5;   // 32 x 8
    #pragma unroll
    for (int i = 0; i < 4; i++)
        tile[ty + i * 8][tx] = W[(size_t)(k0 + ty + i * 8) * N + n0 + tx];
    __syncthreads();
    #pragma unroll
    for (int i = 0; i < 4; i++)
        Wt[(size_t)(n0 + ty + i * 8) * K + k0 + tx] = f2bf(tile[tx][ty + i * 8]);
}

// ---------------------------------------------------------------------------
// Kernel 4: bf16 MFMA GEMM, m97 structure.
// A [M,K] bf16 row-major, Bt [N,K] bf16 row-major (pre-transposed weights).
// 128x128 tile, BK=32, 4 waves (2x2), each wave 64x64 via 4x4 frags of
// mfma_f32_16x16x32_bf16. global_load_lds width=16, linear LDS.
// EPI: 0 = none, 1 = bias + exact GELU, 2 = res + gate * (bias + acc)
// OBF: 1 = bf16 output, 0 = fp32 output
// ---------------------------------------------------------------------------
template<int EPI, int OBF>
__global__ __launch_bounds__(256) void bgemm(
    const unsigned short* __restrict__ A, const unsigned short* __restrict__ Bt,
    const float* __restrict__ bias, const float* __restrict__ res,
    const float* __restrict__ mod, int gate_off,
    void* __restrict__ Cout, int M, int N, int K)
{
    __shared__ unsigned short Atile[128 * 32];
    __shared__ unsigned short Btile[128 * 32];
    const int tid = threadIdx.x;
    const int lane = tid & 63, wid = tid >> 6;
    const int row0 = blockIdx.y * 128, col0 = blockIdx.x * 128;
    const int wr = wid >> 1, wc = wid & 1;     // 2x2 wave grid, 64x64 each

    fx4 acc[4][4];
    const fx4 zero = {0.f, 0.f, 0.f, 0.f};
    #pragma unroll
    for (int m = 0; m < 4; m++)
        #pragma unroll
        for (int n = 0; n < 4; n++) acc[m][n] = zero;

    const int kg = (lane >> 4) * 8;    // k-group base within BK=32
    const int rl = lane & 15;

    for (int k0 = 0; k0 < K; k0 += 32) {
        // stage A,B tiles: 8KB each = 8 chunks of 1KB; wave w does chunks w, w+4
        #pragma unroll
        for (int i = 0; i < 2; i++) {
            int chunk = wid + i * 4;
            int eo = chunk * 512 + lane * 8;         // element offset in tile
            int r = eo >> 5, cc = eo & 31;           // tile row / k-col
            gload_lds16(A  + (size_t)(row0 + r) * K + k0 + cc, Atile + eo);
            gload_lds16(Bt + (size_t)(col0 + r) * K + k0 + cc, Btile + eo);
        }
        __syncthreads();   // compiler emits vmcnt(0) drain before barrier

        bf16x8 af[4], bfr[4];
        #pragma unroll
        for (int m = 0; m < 4; m++)
            af[m] = *(const bf16x8*)(Atile + (wr * 64 + m * 16 + rl) * 32 + kg);
        #pragma unroll
        for (int n = 0; n < 4; n++)
            bfr[n] = *(const bf16x8*)(Btile + (wc * 64 + n * 16 + rl) * 32 + kg);
        #pragma unroll
        for (int m = 0; m < 4; m++)
            #pragma unroll
            for (int n = 0; n < 4; n++)
                acc[m][n] = __builtin_amdgcn_mfma_f32_16x16x32_bf16(
                    af[m], bfr[n], acc[m][n], 0, 0, 0);
        __syncthreads();
    }

    // epilogue; C/D map: col = lane&15, row = (lane>>4)*4 + j  [m89/m91]
    const int b = row0 >> 10;                 // 128 | 1024, never crosses batch
    const int lrow = (lane >> 4) * 4;
    #pragma unroll
    for (int m = 0; m < 4; m++) {
        #pragma unroll
        for (int n = 0; n < 4; n++) {
            int col = col0 + wc * 64 + n * 16 + rl;
            float bv = 0.f, gate = 0.f;
            if (EPI != 0) bv = bias[col];
            if (EPI == 2) gate = mod[(size_t)b * 6144 + gate_off + col];
            #pragma unroll
            for (int j = 0; j < 4; j++) {
                int row = row0 + wr * 64 + m * 16 + lrow + j;
                float v = acc[m][n][j];
                if (EPI == 1) {
                    float u = v + bv;
                    v = 0.5f * u * (1.0f + erff(u * 0.70710678118654752f));
                } else if (EPI == 2) {
                    v = res[(size_t)row * N + col] + gate * (v + bv);
                }
                if (OBF) ((unsigned short*)Cout)[(size_t)row * N + col] = f2bf(v);
                else     ((float*)Cout)[(size_t)row * N + col] = v;
            }
        }
    }
}

// ---------------------------------------------------------------------------
// Kernel 5: flash attention, fp32 compute, bf16 in/out. Thread per q-row.
// grid = B*H*(T/256), block 256. K/V 64-row tiles in LDS (fp32, converted).
// ---------------------------------------------------------------------------
__global__ __launch_bounds__(256) void attn_kernel(
    const unsigned short* __restrict__ qkv, unsigned short* __restrict__ out)
{
    __shared__ float K_lds[64][64];
    __shared__ float V_lds[64][64];
    int qt = blockIdx.x & 3;
    int bh = blockIdx.x >> 2;
    int b = bh >> 4, h = bh & 15;
    int t = qt * 256 + threadIdx.x;
    const unsigned short* base = qkv + (size_t)b * TT * 3 * INNER;

    float q[DH];
    {
        const unsigned short* qp = base + (size_t)t * 3 * INNER + h * DH;
        #pragma unroll
        for (int i = 0; i < 8; i++) {
            uint4 u = ((const uint4*)qp)[i];
            q[i*8+0] = bflo(u.x); q[i*8+1] = bfhi(u.x);
            q[i*8+2] = bflo(u.y); q[i*8+3] = bfhi(u.y);
            q[i*8+4] = bflo(u.z); q[i*8+5] = bfhi(u.z);
            q[i*8+6] = bflo(u.w); q[i*8+7] = bfhi(u.w);
        }
    }
    float o[DH];
    #pragma unroll
    for (int d = 0; d < DH; d++) o[d] = 0.f;
    float m = -INFINITY, l = 0.f;

    for (int kt = 0; kt < TT / 64; kt++) {
        __syncthreads();
        for (int i = threadIdx.x; i < 512; i += 256) {   // 64 rows x 8 chunks
            int r = i >> 3, cq = (i & 7) * 8;
            const unsigned short* kp =
                base + (size_t)(kt * 64 + r) * 3 * INNER + INNER + h * DH + cq;
            uint4 u = *(const uint4*)kp;
            K_lds[r][cq+0] = bflo(u.x); K_lds[r][cq+1] = bfhi(u.x);
            K_lds[r][cq+2] = bflo(u.y); K_lds[r][cq+3] = bfhi(u.y);
            K_lds[r][cq+4] = bflo(u.z); K_lds[r][cq+5] = bfhi(u.z);
            K_lds[r][cq+6] = bflo(u.w); K_lds[r][cq+7] = bfhi(u.w);
            uint4 w = *(const uint4*)(kp + INNER);
            V_lds[r][cq+0] = bflo(w.x); V_lds[r][cq+1] = bfhi(w.x);
            V_lds[r][cq+2] = bflo(w.y); V_lds[r][cq+3] = bfhi(w.y);
            V_lds[r][cq+4] = bflo(w.z); V_lds[r][cq+5] = bfhi(w.z);
            V_lds[r][cq+6] = bflo(w.w); V_lds[r][cq+7] = bfhi(w.w);
        }
        __syncthreads();
        for (int r = 0; r < 64; r++) {
            // 4 independent chains for ILP (1 block/CU -> little TLP)
            float s0 = 0.f, s1 = 0.f, s2 = 0.f, s3 = 0.f;
            #pragma unroll
            for (int d = 0; d < DH; d += 4) {
                s0 += q[d+0] * K_lds[r][d+0];
                s1 += q[d+1] * K_lds[r][d+1];
                s2 += q[d+2] * K_lds[r][d+2];
                s3 += q[d+3] * K_lds[r][d+3];
            }
            float s = ((s0 + s1) + (s2 + s3)) * 0.125f;   // DH^-0.5 = 1/8
            if (s > m) {
                float scale = __expf(m - s);
                #pragma unroll
                for (int d = 0; d < DH; d++) o[d] *= scale;
                l *= scale;
                m = s;
            }
            float p = __expf(s - m);
            l += p;
            #pragma unroll
            for (int d = 0; d < DH; d++) o[d] += p * V_lds[r][d];
        }
    }
    float inv = 1.0f / l;
    unsigned short* op = out + ((size_t)(b * TT + t)) * INNER + h * DH;
    #pragma unroll
    for (int i = 0; i < 8; i++) {
        uint4 u;
        u.x = (unsigned)f2bf(o[i*8+0]*inv) | ((unsigned)f2bf(o[i*8+1]*inv) << 16);
        u.y = (unsigned)f2bf(o[i*8+2]*inv) | ((unsigned)f2bf(o[i*8+3]*inv) << 16);
        u.z = (unsigned)f2bf(o[i*8+4]*inv) | ((unsigned)f2bf(o[i*8+5]*inv) << 16);
        u.w = (unsigned)f2bf(o[i*8+6]*inv) | ((unsigned)f2bf(o[i*8+7]*inv) << 16);
        ((uint4*)op)[i] = u;
    }
}

// ---------------------------------------------------------------------------
// Launch
// ---------------------------------------------------------------------------
extern "C" void kernel_launch(void* const* d_in, const int* in_sizes, int n_in,
                              void* d_out, int out_size, void* d_ws, size_t ws_size,
                              hipStream_t stream)
{
    const float* x     = (const float*)d_in[0];
    const float* c     = (const float*)d_in[1];
    const float* W_mod = (const float*)d_in[2];
    const float* b_mod = (const float*)d_in[3];
    const float* W_qkv = (const float*)d_in[4];
    const float* W_out = (const float*)d_in[5];
    const float* b_out = (const float*)d_in[6];
    const float* W1    = (const float*)d_in[7];
    const float* b1    = (const float*)d_in[8];
    const float* W2    = (const float*)d_in[9];
    const float* b2    = (const float*)d_in[10];
    float* out = (float*)d_out;

    const int M = BB * TT;   // 4096

    // workspace layout (~120 MB)
    char* ws = (char*)d_ws;
    float* mod = (float*)ws;                               // 131072 B
    float* x1  = (float*)(ws + 131072);                    // M*DIM fp32 = 16 MB
    unsigned short* bb = (unsigned short*)(ws + 131072 + (size_t)M * DIM * 4);
    unsigned short* Wqkv_t = bb;  bb += (size_t)3 * INNER * DIM;   // [3072][1024]
    unsigned short* Wout_t = bb;  bb += (size_t)DIM * INNER;       // [1024][1024]
    unsigned short* W1_t   = bb;  bb += (size_t)MLP * DIM;         // [4096][1024]
    unsigned short* W2_t   = bb;  bb += (size_t)DIM * MLP;         // [1024][4096]
    unsigned short* xm     = bb;  bb += (size_t)M * DIM;
    unsigned short* qkvb   = bb;  bb += (size_t)M * 3 * INNER;
    unsigned short* attnb  = bb;  bb += (size_t)M * INNER;
    unsigned short* xm2    = bb;  bb += (size_t)M * DIM;
    unsigned short* hbuf   = bb;  bb += (size_t)M * MLP;

    // 0. weight transpose+convert (fp32 [K,N] -> bf16 [N,K])
    wcvt_kernel<<<dim3(3 * INNER / 32, DIM / 32), 256, 0, stream>>>(W_qkv, Wqkv_t, DIM, 3 * INNER);
    wcvt_kernel<<<dim3(DIM / 32, INNER / 32), 256, 0, stream>>>(W_out, Wout_t, INNER, DIM);
    wcvt_kernel<<<dim3(MLP / 32, DIM / 32), 256, 0, stream>>>(W1, W1_t, DIM, MLP);
    wcvt_kernel<<<dim3(DIM / 32, MLP / 32), 256, 0, stream>>>(W2, W2_t, MLP, DIM);

    // 1. modulation
    mod_kernel<<<24, 256, 0, stream>>>(c, W_mod, b_mod, mod);
    // 2. LN1 + modulate -> bf16
    ln_mod_kernel<<<M, 256, 0, stream>>>(x, mod, OFF_SH_MSA, OFF_SC_MSA, xm);
    // 3. QKV GEMM -> bf16 [M, 3072]
    bgemm<0, 1><<<dim3(3 * INNER / 128, M / 128), 256, 0, stream>>>(
        xm, Wqkv_t, nullptr, nullptr, nullptr, 0, qkvb, M, 3 * INNER, DIM);
    // 4. attention -> bf16 [M, 1024]
    attn_kernel<<<BB * HEADS * (TT / 256), 256, 0, stream>>>(qkvb, attnb);
    // 5. out-proj + gated residual: x1 = x + g_msa*(attn@W_out + b_out)  (fp32)
    bgemm<2, 0><<<dim3(DIM / 128, M / 128), 256, 0, stream>>>(
        attnb, Wout_t, b_out, x, mod, OFF_G_MSA, x1, M, DIM, INNER);
    // 6. LN2 + modulate -> bf16
    ln_mod_kernel<<<M, 256, 0, stream>>>(x1, mod, OFF_SH_MLP, OFF_SC_MLP, xm2);
    // 7. FF1 + bias + exact GELU -> bf16 [M, 4096]
    bgemm<1, 1><<<dim3(MLP / 128, M / 128), 256, 0, stream>>>(
        xm2, W1_t, b1, nullptr, nullptr, 0, hbuf, M, MLP, DIM);
    // 8. FF2 + gated residual -> fp32 out
    bgemm<2, 0><<<dim3(DIM / 128, M / 128), 256, 0, stream>>>(
        hbuf, W2_t, b2, x1, mod, OFF_G_MLP, out, M, DIM, MLP);
}

// Round 5
// 465.643 us; speedup vs baseline: 2.5842x; 2.5842x over previous
//
#include <hip/hip_runtime.h>
#include <hip/hip_bf16.h>
#include <math.h>

// Problem constants
#define BB 4
#define TT 1024
#define DIM 1024
#define HEADS 16
#define DH 64
#define INNER 1024
#define MLP 4096

// mod chunk offsets (per batch row of 6*DIM)
#define OFF_SH_MSA 0
#define OFF_SC_MSA 1024
#define OFF_G_MSA  2048
#define OFF_SH_MLP 3072
#define OFF_SC_MLP 4096
#define OFF_G_MLP  5120

typedef __attribute__((ext_vector_type(8))) short bf16x8;   // 8 bf16 in 4 VGPRs
typedef __attribute__((ext_vector_type(4))) float fx4;      // MFMA accumulator

__device__ __forceinline__ unsigned short f2bf(float f) {
    __hip_bfloat16 h = __float2bfloat16(f);   // RNE
    return __builtin_bit_cast(unsigned short, h);
}
__device__ __forceinline__ float bflo(unsigned u) { return __uint_as_float(u << 16); }
__device__ __forceinline__ float bfhi(unsigned u) { return __uint_as_float(u & 0xffff0000u); }

__device__ __forceinline__ void gload_lds16(const void* g, void* l) {
    __builtin_amdgcn_global_load_lds((const __attribute__((address_space(1))) void*)g,
                                     (__attribute__((address_space(3))) void*)l, 16, 0, 0);
}

// ---------------------------------------------------------------------------
// Kernel 1a: partial mod GEMM: part[ks][b][n] = sum_{k in slice ks} silu(c)@W
// grid (24, 8), 256 thr.  Kernel 1b reduces 8 slices + bias.
// ---------------------------------------------------------------------------
__global__ __launch_bounds__(256) void mod_partial(
    const float* __restrict__ c, const float* __restrict__ W_mod,
    float* __restrict__ part)
{
    __shared__ float sc[BB][128];
    int tid = threadIdx.x;
    int ks = blockIdx.y;
    int k0 = ks * 128;
    for (int i = tid; i < BB * 128; i += 256) {
        int bq = i >> 7, kk = i & 127;
        float v = c[bq * 1024 + k0 + kk];
        sc[bq][kk] = v / (1.0f + __expf(-v));
    }
    __syncthreads();
    int n = blockIdx.x * 256 + tid;   // 0..6143
    float a0 = 0.f, a1 = 0.f, a2 = 0.f, a3 = 0.f;
    for (int kk = 0; kk < 128; kk++) {
        float w = W_mod[(size_t)(k0 + kk) * 6144 + n];
        a0 += sc[0][kk] * w;
        a1 += sc[1][kk] * w;
        a2 += sc[2][kk] * w;
        a3 += sc[3][kk] * w;
    }
    float* p = part + (size_t)ks * 4 * 6144 + n;
    p[0]        = a0;
    p[6144]     = a1;
    p[2 * 6144] = a2;
    p[3 * 6144] = a3;
}

__global__ __launch_bounds__(256) void mod_reduce(
    const float* __restrict__ part, const float* __restrict__ b_mod,
    float* __restrict__ mod)
{
    int n = blockIdx.x * 256 + threadIdx.x;
    float bb = b_mod[n];
    #pragma unroll
    for (int bq = 0; bq < 4; bq++) {
        float a = bb;
        #pragma unroll
        for (int ks = 0; ks < 8; ks++) a += part[(size_t)(ks * 4 + bq) * 6144 + n];
        mod[bq * 6144 + n] = a;
    }
}

// ---------------------------------------------------------------------------
// Kernel 2: fused LayerNorm (affine-free) + modulate -> bf16
// ---------------------------------------------------------------------------
__global__ __launch_bounds__(256) void ln_mod_kernel(
    const float* __restrict__ x, const float* __restrict__ mod,
    int sh_off, int sc_off, unsigned short* __restrict__ out)
{
    int row = blockIdx.x;           // 0..B*T-1
    int b = row >> 10;              // T = 1024
    const float* xr = x + (size_t)row * DIM;
    float4 v = ((const float4*)xr)[threadIdx.x];

    float s1 = v.x + v.y + v.z + v.w;
    float s2 = v.x * v.x + v.y * v.y + v.z * v.z + v.w * v.w;
    #pragma unroll
    for (int off = 32; off > 0; off >>= 1) {
        s1 += __shfl_down(s1, off, 64);
        s2 += __shfl_down(s2, off, 64);
    }
    __shared__ float red[8];
    int lane = threadIdx.x & 63, w = threadIdx.x >> 6;
    if (lane == 0) { red[w] = s1; red[4 + w] = s2; }
    __syncthreads();
    s1 = red[0] + red[1] + red[2] + red[3];
    s2 = red[4] + red[5] + red[6] + red[7];
    float mu = s1 * (1.0f / DIM);
    float var = s2 * (1.0f / DIM) - mu * mu;
    float rs = rsqrtf(var + 1e-5f);

    int col = threadIdx.x * 4;
    const float* mb = mod + (size_t)b * 6144;
    float4 sc4 = *(const float4*)(mb + sc_off + col);
    float4 sh4 = *(const float4*)(mb + sh_off + col);
    ushort4 o;
    o.x = f2bf((v.x - mu) * rs * (1.0f + sc4.x) + sh4.x);
    o.y = f2bf((v.y - mu) * rs * (1.0f + sc4.y) + sh4.y);
    o.z = f2bf((v.z - mu) * rs * (1.0f + sc4.z) + sh4.z);
    o.w = f2bf((v.w - mu) * rs * (1.0f + sc4.w) + sh4.w);
    ((ushort4*)(out + (size_t)row * DIM))[threadIdx.x] = o;
}

// ---------------------------------------------------------------------------
// Kernel 3: weight transpose+convert: W [K,N] fp32 -> Wt [N,K] bf16
// ---------------------------------------------------------------------------
__global__ __launch_bounds__(256) void wcvt_kernel(
    const float* __restrict__ W, unsigned short* __restrict__ Wt, int K, int N)
{
    __shared__ float tile[32][33];
    int n0 = blockIdx.x * 32, k0 = blockIdx.y * 32;
    int tx = threadIdx.x & 31, ty = threadIdx.x >> 5;   // 32 x 8
    #pragma unroll
    for (int i = 0; i < 4; i++)
        tile[ty + i * 8][tx] = W[(size_t)(k0 + ty + i * 8) * N + n0 + tx];
    __syncthreads();
    #pragma unroll
    for (int i = 0; i < 4; i++)
        Wt[(size_t)(n0 + ty + i * 8) * K + k0 + tx] = f2bf(tile[tx][ty + i * 8]);
}

// ---------------------------------------------------------------------------
// Kernel 4: bf16 MFMA GEMM, m97 structure (unchanged from passing round 2).
// ---------------------------------------------------------------------------
template<int EPI, int OBF>
__global__ __launch_bounds__(256) void bgemm(
    const unsigned short* __restrict__ A, const unsigned short* __restrict__ Bt,
    const float* __restrict__ bias, const float* __restrict__ res,
    const float* __restrict__ mod, int gate_off,
    void* __restrict__ Cout, int M, int N, int K)
{
    __shared__ unsigned short Atile[128 * 32];
    __shared__ unsigned short Btile[128 * 32];
    const int tid = threadIdx.x;
    const int lane = tid & 63, wid = tid >> 6;
    const int row0 = blockIdx.y * 128, col0 = blockIdx.x * 128;
    const int wr = wid >> 1, wc = wid & 1;     // 2x2 wave grid, 64x64 each

    fx4 acc[4][4];
    const fx4 zero = {0.f, 0.f, 0.f, 0.f};
    #pragma unroll
    for (int m = 0; m < 4; m++)
        #pragma unroll
        for (int n = 0; n < 4; n++) acc[m][n] = zero;

    const int kg = (lane >> 4) * 8;    // k-group base within BK=32
    const int rl = lane & 15;

    for (int k0 = 0; k0 < K; k0 += 32) {
        #pragma unroll
        for (int i = 0; i < 2; i++) {
            int chunk = wid + i * 4;
            int eo = chunk * 512 + lane * 8;         // element offset in tile
            int r = eo >> 5, cc = eo & 31;           // tile row / k-col
            gload_lds16(A  + (size_t)(row0 + r) * K + k0 + cc, Atile + eo);
            gload_lds16(Bt + (size_t)(col0 + r) * K + k0 + cc, Btile + eo);
        }
        __syncthreads();

        bf16x8 af[4], bfr[4];
        #pragma unroll
        for (int m = 0; m < 4; m++)
            af[m] = *(const bf16x8*)(Atile + (wr * 64 + m * 16 + rl) * 32 + kg);
        #pragma unroll
        for (int n = 0; n < 4; n++)
            bfr[n] = *(const bf16x8*)(Btile + (wc * 64 + n * 16 + rl) * 32 + kg);
        #pragma unroll
        for (int m = 0; m < 4; m++)
            #pragma unroll
            for (int n = 0; n < 4; n++)
                acc[m][n] = __builtin_amdgcn_mfma_f32_16x16x32_bf16(
                    af[m], bfr[n], acc[m][n], 0, 0, 0);
        __syncthreads();
    }

    const int b = row0 >> 10;
    const int lrow = (lane >> 4) * 4;
    #pragma unroll
    for (int m = 0; m < 4; m++) {
        #pragma unroll
        for (int n = 0; n < 4; n++) {
            int col = col0 + wc * 64 + n * 16 + rl;
            float bv = 0.f, gate = 0.f;
            if (EPI != 0) bv = bias[col];
            if (EPI == 2) gate = mod[(size_t)b * 6144 + gate_off + col];
            #pragma unroll
            for (int j = 0; j < 4; j++) {
                int row = row0 + wr * 64 + m * 16 + lrow + j;
                float v = acc[m][n][j];
                if (EPI == 1) {
                    float u = v + bv;
                    v = 0.5f * u * (1.0f + erff(u * 0.70710678118654752f));
                } else if (EPI == 2) {
                    v = res[(size_t)row * N + col] + gate * (v + bv);
                }
                if (OBF) ((unsigned short*)Cout)[(size_t)row * N + col] = f2bf(v);
                else     ((float*)Cout)[(size_t)row * N + col] = v;
            }
        }
    }
}

// ---------------------------------------------------------------------------
// Kernel 5: MFMA flash attention.
// grid = B*H*(T/64) = 1024 blocks, 256 thr (4 waves x 16 q-rows).
// Per kv-tile (64 rows): K staged via global_load_lds (XOR-swizzled source),
// V staged transposed (double-XOR swizzle), QK^T via mfma, in-register
// online softmax (16-lane shfl row-reduce), P via per-wave LDS, PV via mfma.
// Layout conventions identical to bgemm (validated in-context):
//   A-frag: lane holds A[row=lane&15][(lane>>4)*8 + e (+32)]
//   B-frag: lane holds Bt[col=lane&15][(lane>>4)*8 + e (+32)]
//   C/D:    col = lane&15, row = (lane>>4)*4 + j
// ---------------------------------------------------------------------------
__global__ __launch_bounds__(256) void attn_mfma(
    const unsigned short* __restrict__ qkv, unsigned short* __restrict__ out)
{
    __shared__ unsigned short K_l[64 * 64];    // [kr][slot ^ (kr&7)]
    __shared__ unsigned short VT_l[64 * 64];   // [d][slot ^ (d&7) ^ ((d>>3)&7)]
    __shared__ unsigned short P_l[4 * 16 * 64];

    const int tid = threadIdx.x;
    const int lane = tid & 63, w = tid >> 6;
    const int rl = lane & 15, lg = lane >> 4;     // 0..15 / 0..3
    const int qi = blockIdx.x & 15;
    const int bh = blockIdx.x >> 4;
    const int b = bh >> 4, h = bh & 15;

    const unsigned short* base = qkv + (size_t)b * TT * 3 * INNER + h * DH;

    // Q fragments (held in registers for the whole kernel)
    const int qrow = qi * 64 + w * 16 + rl;
    bf16x8 qf[2];
    qf[0] = *(const bf16x8*)(base + (size_t)qrow * 3 * INNER + lg * 8);
    qf[1] = *(const bf16x8*)(base + (size_t)qrow * 3 * INNER + lg * 8 + 32);

    const fx4 z4 = {0.f, 0.f, 0.f, 0.f};
    fx4 acc_o[4];
    #pragma unroll
    for (int db = 0; db < 4; db++) acc_o[db] = z4;
    float mrow[4] = {-INFINITY, -INFINITY, -INFINITY, -INFINITY};
    float lrow[4] = {0.f, 0.f, 0.f, 0.f};

    unsigned short* Pw = P_l + w * 1024;

    for (int kt = 0; kt < 16; kt++) {
        __syncthreads();
        // ---- stage K tile [64 kr][64 d] via global_load_lds, swizzled source
        #pragma unroll
        for (int i = 0; i < 2; i++) {
            int instr = w * 2 + i;
            int row = instr * 8 + (lane >> 3);
            int slog = (lane & 7) ^ (lane >> 3);      // logical 16B slot
            gload_lds16(base + (size_t)(kt * 64 + row) * 3 * INNER + INNER + slog * 8,
                        K_l + instr * 512);
        }
        // ---- stage V tile transposed: VT[d][k], conflict-free swizzle
        #pragma unroll
        for (int hh = 0; hh < 2; hh++) {
            int dc = tid & 7;                    // d-chunk (8 d's)
            int kr = (tid >> 3) + hh * 32;       // k row
            const unsigned short* vg =
                base + (size_t)(kt * 64 + kr) * 3 * INNER + 2 * INNER + dc * 8;
            uint4 vv = *(const uint4*)vg;
            unsigned wds[4] = {vv.x, vv.y, vv.z, vv.w};
            #pragma unroll
            for (int j = 0; j < 8; j++) {
                unsigned word = wds[j >> 1];
                unsigned short e = (j & 1) ? (unsigned short)(word >> 16)
                                           : (unsigned short)(word & 0xffff);
                int d = dc * 8 + j;
                int phys = ((kr >> 3) ^ j ^ dc) & 7;
                VT_l[d * 64 + phys * 8 + (kr & 7)] = e;
            }
        }
        __syncthreads();

        // ---- QK^T: S[16 q][64 k] per wave
        fx4 sacc[4];
        #pragma unroll
        for (int kb = 0; kb < 4; kb++) sacc[kb] = z4;
        #pragma unroll
        for (int half = 0; half < 2; half++) {
            #pragma unroll
            for (int kb = 0; kb < 4; kb++) {
                int kr = kb * 16 + rl;
                bf16x8 kf = *(const bf16x8*)(
                    K_l + kr * 64 + (((lg + half * 4) ^ (kr & 7)) & 7) * 8);
                sacc[kb] = __builtin_amdgcn_mfma_f32_16x16x32_bf16(
                    qf[half], kf, sacc[kb], 0, 0, 0);
            }
        }

        // ---- online softmax (rows = (lg*4+j), cols distributed over 16 lanes)
        #pragma unroll
        for (int kb = 0; kb < 4; kb++) sacc[kb] *= 0.125f;   // DH^-0.5

        float f[4], p[4][4];
        #pragma unroll
        for (int j = 0; j < 4; j++) {
            float t = fmaxf(fmaxf(sacc[0][j], sacc[1][j]),
                            fmaxf(sacc[2][j], sacc[3][j]));
            t = fmaxf(t, __shfl_xor(t, 1));
            t = fmaxf(t, __shfl_xor(t, 2));
            t = fmaxf(t, __shfl_xor(t, 4));
            t = fmaxf(t, __shfl_xor(t, 8));
            float nm = fmaxf(mrow[j], t);
            f[j] = __expf(mrow[j] - nm);    // exp(-inf)=0 on first tile
            mrow[j] = nm;
        }
        #pragma unroll
        for (int kb = 0; kb < 4; kb++)
            #pragma unroll
            for (int j = 0; j < 4; j++)
                p[kb][j] = __expf(sacc[kb][j] - mrow[j]);
        #pragma unroll
        for (int j = 0; j < 4; j++) {
            float s = (p[0][j] + p[1][j]) + (p[2][j] + p[3][j]);
            s += __shfl_xor(s, 1);
            s += __shfl_xor(s, 2);
            s += __shfl_xor(s, 4);
            s += __shfl_xor(s, 8);
            lrow[j] = lrow[j] * f[j] + s;
        }
        fx4 fv = {f[0], f[1], f[2], f[3]};
        #pragma unroll
        for (int db = 0; db < 4; db++) acc_o[db] *= fv;

        // ---- P -> per-wave LDS (bf16, swizzled)
        #pragma unroll
        for (int kb = 0; kb < 4; kb++) {
            #pragma unroll
            for (int j = 0; j < 4; j++) {
                int q16 = lg * 4 + j;
                int phys = ((kb * 2 + (rl >> 3)) ^ (q16 & 7)) & 7;
                Pw[q16 * 64 + phys * 8 + (rl & 7)] = f2bf(p[kb][j]);
            }
        }
        asm volatile("s_waitcnt lgkmcnt(0)" ::: "memory");

        // ---- PV: O += P @ V
        #pragma unroll
        for (int half = 0; half < 2; half++) {
            bf16x8 pf = *(const bf16x8*)(
                Pw + rl * 64 + (((lg + half * 4) ^ (rl & 7)) & 7) * 8);
            #pragma unroll
            for (int db = 0; db < 4; db++) {
                int d = db * 16 + rl;
                bf16x8 vf = *(const bf16x8*)(
                    VT_l + d * 64 +
                    ((((lg + half * 4) ^ (d & 7)) ^ ((d >> 3) & 7)) & 7) * 8);
                acc_o[db] = __builtin_amdgcn_mfma_f32_16x16x32_bf16(
                    pf, vf, acc_o[db], 0, 0, 0);
            }
        }
    }

    // ---- normalize + write out (bf16)
    float inv[4];
    #pragma unroll
    for (int j = 0; j < 4; j++) inv[j] = 1.0f / lrow[j];
    #pragma unroll
    for (int db = 0; db < 4; db++) {
        #pragma unroll
        for (int j = 0; j < 4; j++) {
            int row = qi * 64 + w * 16 + lg * 4 + j;
            out[(size_t)(b * TT + row) * INNER + h * DH + db * 16 + rl] =
                f2bf(acc_o[db][j] * inv[j]);
        }
    }
}

// ---------------------------------------------------------------------------
// Launch
// ---------------------------------------------------------------------------
extern "C" void kernel_launch(void* const* d_in, const int* in_sizes, int n_in,
                              void* d_out, int out_size, void* d_ws, size_t ws_size,
                              hipStream_t stream)
{
    const float* x     = (const float*)d_in[0];
    const float* c     = (const float*)d_in[1];
    const float* W_mod = (const float*)d_in[2];
    const float* b_mod = (const float*)d_in[3];
    const float* W_qkv = (const float*)d_in[4];
    const float* W_out = (const float*)d_in[5];
    const float* b_out = (const float*)d_in[6];
    const float* W1    = (const float*)d_in[7];
    const float* b1    = (const float*)d_in[8];
    const float* W2    = (const float*)d_in[9];
    const float* b2    = (const float*)d_in[10];
    float* out = (float*)d_out;

    const int M = BB * TT;   // 4096

    // workspace layout
    char* ws = (char*)d_ws;
    float* mod      = (float*)ws;                          // 98 KB (pad 128 KB)
    float* mod_part = (float*)(ws + 131072);               // 786 KB (pad to 1 MB)
    float* x1       = (float*)(ws + 1048576);              // 16 MB fp32
    unsigned short* bb = (unsigned short*)(ws + 1048576 + (size_t)M * DIM * 4);
    unsigned short* Wqkv_t = bb;  bb += (size_t)3 * INNER * DIM;
    unsigned short* Wout_t = bb;  bb += (size_t)DIM * INNER;
    unsigned short* W1_t   = bb;  bb += (size_t)MLP * DIM;
    unsigned short* W2_t   = bb;  bb += (size_t)DIM * MLP;
    unsigned short* xm     = bb;  bb += (size_t)M * DIM;
    unsigned short* qkvb   = bb;  bb += (size_t)M * 3 * INNER;
    unsigned short* attnb  = bb;  bb += (size_t)M * INNER;
    unsigned short* xm2    = bb;  bb += (size_t)M * DIM;
    unsigned short* hbuf   = bb;  bb += (size_t)M * MLP;

    // 0. weight transpose+convert
    wcvt_kernel<<<dim3(3 * INNER / 32, DIM / 32), 256, 0, stream>>>(W_qkv, Wqkv_t, DIM, 3 * INNER);
    wcvt_kernel<<<dim3(DIM / 32, INNER / 32), 256, 0, stream>>>(W_out, Wout_t, INNER, DIM);
    wcvt_kernel<<<dim3(MLP / 32, DIM / 32), 256, 0, stream>>>(W1, W1_t, DIM, MLP);
    wcvt_kernel<<<dim3(DIM / 32, MLP / 32), 256, 0, stream>>>(W2, W2_t, MLP, DIM);

    // 1. modulation (k-split for CU coverage)
    mod_partial<<<dim3(24, 8), 256, 0, stream>>>(c, W_mod, mod_part);
    mod_reduce<<<24, 256, 0, stream>>>(mod_part, b_mod, mod);
    // 2. LN1 + modulate -> bf16
    ln_mod_kernel<<<M, 256, 0, stream>>>(x, mod, OFF_SH_MSA, OFF_SC_MSA, xm);
    // 3. QKV GEMM -> bf16 [M, 3072]
    bgemm<0, 1><<<dim3(3 * INNER / 128, M / 128), 256, 0, stream>>>(
        xm, Wqkv_t, nullptr, nullptr, nullptr, 0, qkvb, M, 3 * INNER, DIM);
    // 4. MFMA flash attention -> bf16 [M, 1024]
    attn_mfma<<<BB * HEADS * (TT / 64), 256, 0, stream>>>(qkvb, attnb);
    // 5. out-proj + gated residual (fp32)
    bgemm<2, 0><<<dim3(DIM / 128, M / 128), 256, 0, stream>>>(
        attnb, Wout_t, b_out, x, mod, OFF_G_MSA, x1, M, DIM, INNER);
    // 6. LN2 + modulate -> bf16
    ln_mod_kernel<<<M, 256, 0, stream>>>(x1, mod, OFF_SH_MLP, OFF_SC_MLP, xm2);
    // 7. FF1 + bias + exact GELU -> bf16 [M, 4096]
    bgemm<1, 1><<<dim3(MLP / 128, M / 128), 256, 0, stream>>>(
        xm2, W1_t, b1, nullptr, nullptr, 0, hbuf, M, MLP, DIM);
    // 8. FF2 + gated residual -> fp32 out
    bgemm<2, 0><<<dim3(DIM / 128, M / 128), 256, 0, stream>>>(
        hbuf, W2_t, b2, x1, mod, OFF_G_MLP, out, M, DIM, MLP);
}

// Round 6
// 436.905 us; speedup vs baseline: 2.7542x; 1.0658x over previous
//
#include <hip/hip_runtime.h>
#include <hip/hip_bf16.h>
#include <math.h>

// Problem constants
#define BB 4
#define TT 1024
#define DIM 1024
#define HEADS 16
#define DH 64
#define INNER 1024
#define MLP 4096

// mod chunk offsets (per batch row of 6*DIM)
#define OFF_SH_MSA 0
#define OFF_SC_MSA 1024
#define OFF_G_MSA  2048
#define OFF_SH_MLP 3072
#define OFF_SC_MLP 4096
#define OFF_G_MLP  5120

typedef __attribute__((ext_vector_type(8))) short bf16x8;   // 8 bf16 in 4 VGPRs
typedef __attribute__((ext_vector_type(4))) float fx4;      // MFMA accumulator

__device__ __forceinline__ unsigned short f2bf(float f) {
    __hip_bfloat16 h = __float2bfloat16(f);   // RNE
    return __builtin_bit_cast(unsigned short, h);
}

__device__ __forceinline__ void gload_lds16(const void* g, void* l) {
    __builtin_amdgcn_global_load_lds((const __attribute__((address_space(1))) void*)g,
                                     (__attribute__((address_space(3))) void*)l, 16, 0, 0);
}

// ---------------------------------------------------------------------------
// Kernel 1a: partial mod GEMM: part[ks][b][n] = sum_{k in slice ks} silu(c)@W
// ---------------------------------------------------------------------------
__global__ __launch_bounds__(256) void mod_partial(
    const float* __restrict__ c, const float* __restrict__ W_mod,
    float* __restrict__ part)
{
    __shared__ float sc[BB][128];
    int tid = threadIdx.x;
    int ks = blockIdx.y;
    int k0 = ks * 128;
    for (int i = tid; i < BB * 128; i += 256) {
        int bq = i >> 7, kk = i & 127;
        float v = c[bq * 1024 + k0 + kk];
        sc[bq][kk] = v / (1.0f + __expf(-v));
    }
    __syncthreads();
    int n = blockIdx.x * 256 + tid;   // 0..6143
    float a0 = 0.f, a1 = 0.f, a2 = 0.f, a3 = 0.f;
    for (int kk = 0; kk < 128; kk++) {
        float w = W_mod[(size_t)(k0 + kk) * 6144 + n];
        a0 += sc[0][kk] * w;
        a1 += sc[1][kk] * w;
        a2 += sc[2][kk] * w;
        a3 += sc[3][kk] * w;
    }
    float* p = part + (size_t)ks * 4 * 6144 + n;
    p[0]        = a0;
    p[6144]     = a1;
    p[2 * 6144] = a2;
    p[3 * 6144] = a3;
}

__global__ __launch_bounds__(256) void mod_reduce(
    const float* __restrict__ part, const float* __restrict__ b_mod,
    float* __restrict__ mod)
{
    int n = blockIdx.x * 256 + threadIdx.x;
    float bb = b_mod[n];
    #pragma unroll
    for (int bq = 0; bq < 4; bq++) {
        float a = bb;
        #pragma unroll
        for (int ks = 0; ks < 8; ks++) a += part[(size_t)(ks * 4 + bq) * 6144 + n];
        mod[bq * 6144 + n] = a;
    }
}

// ---------------------------------------------------------------------------
// Kernel 2: fused LayerNorm (affine-free) + modulate -> bf16
// ---------------------------------------------------------------------------
__global__ __launch_bounds__(256) void ln_mod_kernel(
    const float* __restrict__ x, const float* __restrict__ mod,
    int sh_off, int sc_off, unsigned short* __restrict__ out)
{
    int row = blockIdx.x;           // 0..B*T-1
    int b = row >> 10;              // T = 1024
    const float* xr = x + (size_t)row * DIM;
    float4 v = ((const float4*)xr)[threadIdx.x];

    float s1 = v.x + v.y + v.z + v.w;
    float s2 = v.x * v.x + v.y * v.y + v.z * v.z + v.w * v.w;
    #pragma unroll
    for (int off = 32; off > 0; off >>= 1) {
        s1 += __shfl_down(s1, off, 64);
        s2 += __shfl_down(s2, off, 64);
    }
    __shared__ float red[8];
    int lane = threadIdx.x & 63, w = threadIdx.x >> 6;
    if (lane == 0) { red[w] = s1; red[4 + w] = s2; }
    __syncthreads();
    s1 = red[0] + red[1] + red[2] + red[3];
    s2 = red[4] + red[5] + red[6] + red[7];
    float mu = s1 * (1.0f / DIM);
    float var = s2 * (1.0f / DIM) - mu * mu;
    float rs = rsqrtf(var + 1e-5f);

    int col = threadIdx.x * 4;
    const float* mb = mod + (size_t)b * 6144;
    float4 sc4 = *(const float4*)(mb + sc_off + col);
    float4 sh4 = *(const float4*)(mb + sh_off + col);
    ushort4 o;
    o.x = f2bf((v.x - mu) * rs * (1.0f + sc4.x) + sh4.x);
    o.y = f2bf((v.y - mu) * rs * (1.0f + sc4.y) + sh4.y);
    o.z = f2bf((v.z - mu) * rs * (1.0f + sc4.z) + sh4.z);
    o.w = f2bf((v.w - mu) * rs * (1.0f + sc4.w) + sh4.w);
    ((ushort4*)(out + (size_t)row * DIM))[threadIdx.x] = o;
}

// ---------------------------------------------------------------------------
// Kernel 3: fused weight transpose+convert for all 4 weights in ONE dispatch.
// Each 32x32 tile: W [K,N] fp32 -> Wt [N,K] bf16.
// Tile ranges: Wqkv 3072, Wout 1024, W1 4096, W2 4096  (total 12288)
// ---------------------------------------------------------------------------
__global__ __launch_bounds__(256) void wcvt_all(
    const float* __restrict__ Wqkv, const float* __restrict__ Wout,
    const float* __restrict__ W1,   const float* __restrict__ W2,
    unsigned short* __restrict__ oQ, unsigned short* __restrict__ oO,
    unsigned short* __restrict__ o1, unsigned short* __restrict__ o2)
{
    __shared__ float tile[32][33];
    int t = blockIdx.x;
    const float* W; unsigned short* O; int K, N, nx;
    if (t < 3072)      {            W = Wqkv; O = oQ; K = 1024; N = 3072; nx = 96;  }
    else if (t < 4096) { t -= 3072; W = Wout; O = oO; K = 1024; N = 1024; nx = 32;  }
    else if (t < 8192) { t -= 4096; W = W1;   O = o1; K = 1024; N = 4096; nx = 128; }
    else               { t -= 8192; W = W2;   O = o2; K = 4096; N = 1024; nx = 32;  }
    int n0 = (t % nx) * 32, k0 = (t / nx) * 32;
    int tx = threadIdx.x & 31, ty = threadIdx.x >> 5;   // 32 x 8
    #pragma unroll
    for (int i = 0; i < 4; i++)
        tile[ty + i * 8][tx] = W[(size_t)(k0 + ty + i * 8) * N + n0 + tx];
    __syncthreads();
    #pragma unroll
    for (int i = 0; i < 4; i++)
        O[(size_t)(n0 + ty + i * 8) * K + k0 + tx] = f2bf(tile[tx][ty + i * 8]);
}

// ---------------------------------------------------------------------------
// Kernel 4: bf16 MFMA GEMM, m97 structure + XCD swizzle + templated BN.
// A [M,K] bf16 row-major, Bt [N,K] bf16 row-major.
// 128 x (NF*32) tile, BK=32, 4 waves (2x2); wave = 64 rows x NF*16 cols.
// NF=4 -> BN=128 (original); NF=2 -> BN=64 (2x grid for small-N GEMMs).
// EPI: 0 = none, 1 = bias+gelu, 2 = res + gate*(bias+acc).  OBF: bf16/f32 out.
// Grid MUST be divisible by 8 (XCD swizzle bijectivity).
// ---------------------------------------------------------------------------
template<int EPI, int OBF, int NF>
__global__ __launch_bounds__(256) void bgemm(
    const unsigned short* __restrict__ A, const unsigned short* __restrict__ Bt,
    const float* __restrict__ bias, const float* __restrict__ res,
    const float* __restrict__ mod, int gate_off,
    void* __restrict__ Cout, int M, int N, int K)
{
    __shared__ unsigned short Atile[128 * 32];
    __shared__ unsigned short Btile[NF * 32 * 32];
    const int tid = threadIdx.x;
    const int lane = tid & 63, wid = tid >> 6;

    // XCD chunked swizzle: contiguous logical tiles per XCD (nwg % 8 == 0)
    const int gx = gridDim.x;
    const int nwg = gx * gridDim.y;
    const int bid = blockIdx.y * gx + blockIdx.x;
    const int swz = (bid & 7) * (nwg >> 3) + (bid >> 3);
    const int row0 = (swz / gx) * 128;
    const int col0 = (swz % gx) * (NF * 32);

    const int wr = wid >> 1, wc = wid & 1;     // 2x2 wave grid

    fx4 acc[4][NF];
    const fx4 zero = {0.f, 0.f, 0.f, 0.f};
    #pragma unroll
    for (int m = 0; m < 4; m++)
        #pragma unroll
        for (int n = 0; n < NF; n++) acc[m][n] = zero;

    const int kg = (lane >> 4) * 8;    // k-group base within BK=32
    const int rl = lane & 15;

    for (int k0 = 0; k0 < K; k0 += 32) {
        // A tile: 8KB = 8 chunks of 1KB; wave w does chunks w, w+4
        #pragma unroll
        for (int i = 0; i < 2; i++) {
            int chunk = wid + i * 4;
            int eo = chunk * 512 + lane * 8;
            int r = eo >> 5, cc = eo & 31;
            gload_lds16(A + (size_t)(row0 + r) * K + k0 + cc, Atile + eo);
        }
        // B tile: NF*2 chunks of 1KB
        #pragma unroll
        for (int i = 0; i < (NF >> 1); i++) {
            int chunk = wid + i * 4;
            int eo = chunk * 512 + lane * 8;
            int r = eo >> 5, cc = eo & 31;
            gload_lds16(Bt + (size_t)(col0 + r) * K + k0 + cc, Btile + eo);
        }
        __syncthreads();

        bf16x8 af[4], bfr[NF];
        #pragma unroll
        for (int m = 0; m < 4; m++)
            af[m] = *(const bf16x8*)(Atile + (wr * 64 + m * 16 + rl) * 32 + kg);
        #pragma unroll
        for (int n = 0; n < NF; n++)
            bfr[n] = *(const bf16x8*)(Btile + (wc * (NF * 16) + n * 16 + rl) * 32 + kg);
        #pragma unroll
        for (int m = 0; m < 4; m++)
            #pragma unroll
            for (int n = 0; n < NF; n++)
                acc[m][n] = __builtin_amdgcn_mfma_f32_16x16x32_bf16(
                    af[m], bfr[n], acc[m][n], 0, 0, 0);
        __syncthreads();
    }

    // epilogue; C/D map: col = lane&15, row = (lane>>4)*4 + j  [m89/m91]
    const int b = row0 >> 10;                 // 128 | 1024, never crosses batch
    const int lrow = (lane >> 4) * 4;
    #pragma unroll
    for (int m = 0; m < 4; m++) {
        #pragma unroll
        for (int n = 0; n < NF; n++) {
            int col = col0 + wc * (NF * 16) + n * 16 + rl;
            float bv = 0.f, gate = 0.f;
            if (EPI != 0) bv = bias[col];
            if (EPI == 2) gate = mod[(size_t)b * 6144 + gate_off + col];
            #pragma unroll
            for (int j = 0; j < 4; j++) {
                int row = row0 + wr * 64 + m * 16 + lrow + j;
                float v = acc[m][n][j];
                if (EPI == 1) {
                    float u = v + bv;
                    v = 0.5f * u * (1.0f + erff(u * 0.70710678118654752f));
                } else if (EPI == 2) {
                    v = res[(size_t)row * N + col] + gate * (v + bv);
                }
                if (OBF) ((unsigned short*)Cout)[(size_t)row * N + col] = f2bf(v);
                else     ((float*)Cout)[(size_t)row * N + col] = v;
            }
        }
    }
}

// ---------------------------------------------------------------------------
// Kernel 5: MFMA flash attention (verified round 5) + XCD swizzle.
// grid = 1024 blocks, 256 thr (4 waves x 16 q-rows).
// ---------------------------------------------------------------------------
__global__ __launch_bounds__(256) void attn_mfma(
    const unsigned short* __restrict__ qkv, unsigned short* __restrict__ out)
{
    __shared__ unsigned short K_l[64 * 64];    // [kr][slot ^ (kr&7)]
    __shared__ unsigned short VT_l[64 * 64];   // [d][slot ^ (d&7) ^ ((d>>3)&7)]
    __shared__ unsigned short P_l[4 * 16 * 64];

    const int tid = threadIdx.x;
    const int lane = tid & 63, w = tid >> 6;
    const int rl = lane & 15, lg = lane >> 4;     // 0..15 / 0..3

    // XCD swizzle: group the 16 q-tiles of each (b,h) on one XCD (KV L2-hot)
    const int bid = blockIdx.x;                   // nwg = 1024
    const int swz = (bid & 7) * 128 + (bid >> 3);
    const int qi = swz & 15;
    const int bh = swz >> 4;
    const int b = bh >> 4, h = bh & 15;

    const unsigned short* base = qkv + (size_t)b * TT * 3 * INNER + h * DH;

    // Q fragments (held in registers for the whole kernel)
    const int qrow = qi * 64 + w * 16 + rl;
    bf16x8 qf[2];
    qf[0] = *(const bf16x8*)(base + (size_t)qrow * 3 * INNER + lg * 8);
    qf[1] = *(const bf16x8*)(base + (size_t)qrow * 3 * INNER + lg * 8 + 32);

    const fx4 z4 = {0.f, 0.f, 0.f, 0.f};
    fx4 acc_o[4];
    #pragma unroll
    for (int db = 0; db < 4; db++) acc_o[db] = z4;
    float mrow[4] = {-INFINITY, -INFINITY, -INFINITY, -INFINITY};
    float lrow[4] = {0.f, 0.f, 0.f, 0.f};

    unsigned short* Pw = P_l + w * 1024;

    for (int kt = 0; kt < 16; kt++) {
        __syncthreads();
        // ---- stage K tile [64 kr][64 d] via global_load_lds, swizzled source
        #pragma unroll
        for (int i = 0; i < 2; i++) {
            int instr = w * 2 + i;
            int row = instr * 8 + (lane >> 3);
            int slog = (lane & 7) ^ (lane >> 3);      // logical 16B slot
            gload_lds16(base + (size_t)(kt * 64 + row) * 3 * INNER + INNER + slog * 8,
                        K_l + instr * 512);
        }
        // ---- stage V tile transposed: VT[d][k], conflict-free swizzle
        #pragma unroll
        for (int hh = 0; hh < 2; hh++) {
            int dc = tid & 7;                    // d-chunk (8 d's)
            int kr = (tid >> 3) + hh * 32;       // k row
            const unsigned short* vg =
                base + (size_t)(kt * 64 + kr) * 3 * INNER + 2 * INNER + dc * 8;
            uint4 vv = *(const uint4*)vg;
            unsigned wds[4] = {vv.x, vv.y, vv.z, vv.w};
            #pragma unroll
            for (int j = 0; j < 8; j++) {
                unsigned word = wds[j >> 1];
                unsigned short e = (j & 1) ? (unsigned short)(word >> 16)
                                           : (unsigned short)(word & 0xffff);
                int d = dc * 8 + j;
                int phys = ((kr >> 3) ^ j ^ dc) & 7;
                VT_l[d * 64 + phys * 8 + (kr & 7)] = e;
            }
        }
        __syncthreads();

        // ---- QK^T: S[16 q][64 k] per wave
        fx4 sacc[4];
        #pragma unroll
        for (int kb = 0; kb < 4; kb++) sacc[kb] = z4;
        #pragma unroll
        for (int half = 0; half < 2; half++) {
            #pragma unroll
            for (int kb = 0; kb < 4; kb++) {
                int kr = kb * 16 + rl;
                bf16x8 kf = *(const bf16x8*)(
                    K_l + kr * 64 + (((lg + half * 4) ^ (kr & 7)) & 7) * 8);
                sacc[kb] = __builtin_amdgcn_mfma_f32_16x16x32_bf16(
                    qf[half], kf, sacc[kb], 0, 0, 0);
            }
        }

        // ---- online softmax (rows = lg*4+j, cols over 16 lanes)
        #pragma unroll
        for (int kb = 0; kb < 4; kb++) sacc[kb] *= 0.125f;   // DH^-0.5

        float f[4], p[4][4];
        #pragma unroll
        for (int j = 0; j < 4; j++) {
            float t = fmaxf(fmaxf(sacc[0][j], sacc[1][j]),
                            fmaxf(sacc[2][j], sacc[3][j]));
            t = fmaxf(t, __shfl_xor(t, 1));
            t = fmaxf(t, __shfl_xor(t, 2));
            t = fmaxf(t, __shfl_xor(t, 4));
            t = fmaxf(t, __shfl_xor(t, 8));
            float nm = fmaxf(mrow[j], t);
            f[j] = __expf(mrow[j] - nm);    // exp(-inf)=0 on first tile
            mrow[j] = nm;
        }
        #pragma unroll
        for (int kb = 0; kb < 4; kb++)
            #pragma unroll
            for (int j = 0; j < 4; j++)
                p[kb][j] = __expf(sacc[kb][j] - mrow[j]);
        #pragma unroll
        for (int j = 0; j < 4; j++) {
            float s = (p[0][j] + p[1][j]) + (p[2][j] + p[3][j]);
            s += __shfl_xor(s, 1);
            s += __shfl_xor(s, 2);
            s += __shfl_xor(s, 4);
            s += __shfl_xor(s, 8);
            lrow[j] = lrow[j] * f[j] + s;
        }
        fx4 fv = {f[0], f[1], f[2], f[3]};
        #pragma unroll
        for (int db = 0; db < 4; db++) acc_o[db] *= fv;

        // ---- P -> per-wave LDS (bf16, swizzled)
        #pragma unroll
        for (int kb = 0; kb < 4; kb++) {
            #pragma unroll
            for (int j = 0; j < 4; j++) {
                int q16 = lg * 4 + j;
                int phys = ((kb * 2 + (rl >> 3)) ^ (q16 & 7)) & 7;
                Pw[q16 * 64 + phys * 8 + (rl & 7)] = f2bf(p[kb][j]);
            }
        }
        asm volatile("s_waitcnt lgkmcnt(0)" ::: "memory");

        // ---- PV: O += P @ V
        #pragma unroll
        for (int half = 0; half < 2; half++) {
            bf16x8 pf = *(const bf16x8*)(
                Pw + rl * 64 + (((lg + half * 4) ^ (rl & 7)) & 7) * 8);
            #pragma unroll
            for (int db = 0; db < 4; db++) {
                int d = db * 16 + rl;
                bf16x8 vf = *(const bf16x8*)(
                    VT_l + d * 64 +
                    ((((lg + half * 4) ^ (d & 7)) ^ ((d >> 3) & 7)) & 7) * 8);
                acc_o[db] = __builtin_amdgcn_mfma_f32_16x16x32_bf16(
                    pf, vf, acc_o[db], 0, 0, 0);
            }
        }
    }

    // ---- normalize + write out (bf16)
    float inv[4];
    #pragma unroll
    for (int j = 0; j < 4; j++) inv[j] = 1.0f / lrow[j];
    #pragma unroll
    for (int db = 0; db < 4; db++) {
        #pragma unroll
        for (int j = 0; j < 4; j++) {
            int row = qi * 64 + w * 16 + lg * 4 + j;
            out[(size_t)(b * TT + row) * INNER + h * DH + db * 16 + rl] =
                f2bf(acc_o[db][j] * inv[j]);
        }
    }
}

// ---------------------------------------------------------------------------
// Launch
// ---------------------------------------------------------------------------
extern "C" void kernel_launch(void* const* d_in, const int* in_sizes, int n_in,
                              void* d_out, int out_size, void* d_ws, size_t ws_size,
                              hipStream_t stream)
{
    const float* x     = (const float*)d_in[0];
    const float* c     = (const float*)d_in[1];
    const float* W_mod = (const float*)d_in[2];
    const float* b_mod = (const float*)d_in[3];
    const float* W_qkv = (const float*)d_in[4];
    const float* W_out = (const float*)d_in[5];
    const float* b_out = (const float*)d_in[6];
    const float* W1    = (const float*)d_in[7];
    const float* b1    = (const float*)d_in[8];
    const float* W2    = (const float*)d_in[9];
    const float* b2    = (const float*)d_in[10];
    float* out = (float*)d_out;

    const int M = BB * TT;   // 4096

    // workspace layout
    char* ws = (char*)d_ws;
    float* mod      = (float*)ws;                          // 98 KB (pad 128 KB)
    float* mod_part = (float*)(ws + 131072);               // 786 KB (pad to 1 MB)
    float* x1       = (float*)(ws + 1048576);              // 16 MB fp32
    unsigned short* bb = (unsigned short*)(ws + 1048576 + (size_t)M * DIM * 4);
    unsigned short* Wqkv_t = bb;  bb += (size_t)3 * INNER * DIM;
    unsigned short* Wout_t = bb;  bb += (size_t)DIM * INNER;
    unsigned short* W1_t   = bb;  bb += (size_t)MLP * DIM;
    unsigned short* W2_t   = bb;  bb += (size_t)DIM * MLP;
    unsigned short* xm     = bb;  bb += (size_t)M * DIM;
    unsigned short* qkvb   = bb;  bb += (size_t)M * 3 * INNER;
    unsigned short* attnb  = bb;  bb += (size_t)M * INNER;
    unsigned short* xm2    = bb;  bb += (size_t)M * DIM;
    unsigned short* hbuf   = bb;  bb += (size_t)M * MLP;

    // 0. weight transpose+convert (single dispatch, 12288 tiles)
    wcvt_all<<<12288, 256, 0, stream>>>(W_qkv, W_out, W1, W2,
                                        Wqkv_t, Wout_t, W1_t, W2_t);

    // 1. modulation (k-split for CU coverage)
    mod_partial<<<dim3(24, 8), 256, 0, stream>>>(c, W_mod, mod_part);
    mod_reduce<<<24, 256, 0, stream>>>(mod_part, b_mod, mod);
    // 2. LN1 + modulate -> bf16
    ln_mod_kernel<<<M, 256, 0, stream>>>(x, mod, OFF_SH_MSA, OFF_SC_MSA, xm);
    // 3. QKV GEMM -> bf16 [M, 3072]   (grid 24x32 = 768, %8==0)
    bgemm<0, 1, 4><<<dim3(3 * INNER / 128, M / 128), 256, 0, stream>>>(
        xm, Wqkv_t, nullptr, nullptr, nullptr, 0, qkvb, M, 3 * INNER, DIM);
    // 4. MFMA flash attention -> bf16 [M, 1024]
    attn_mfma<<<BB * HEADS * (TT / 64), 256, 0, stream>>>(qkvb, attnb);
    // 5. out-proj + gated residual (fp32), BN=64 (grid 16x32 = 512, 2 blk/CU)
    bgemm<2, 0, 2><<<dim3(DIM / 64, M / 128), 256, 0, stream>>>(
        attnb, Wout_t, b_out, x, mod, OFF_G_MSA, x1, M, DIM, INNER);
    // 6. LN2 + modulate -> bf16
    ln_mod_kernel<<<M, 256, 0, stream>>>(x1, mod, OFF_SH_MLP, OFF_SC_MLP, xm2);
    // 7. FF1 + bias + exact GELU -> bf16 [M, 4096]  (grid 32x32 = 1024)
    bgemm<1, 1, 4><<<dim3(MLP / 128, M / 128), 256, 0, stream>>>(
        xm2, W1_t, b1, nullptr, nullptr, 0, hbuf, M, MLP, DIM);
    // 8. FF2 + gated residual -> fp32 out, BN=64 (grid 16x32 = 512, 2 blk/CU)
    bgemm<2, 0, 2><<<dim3(DIM / 64, M / 128), 256, 0, stream>>>(
        hbuf, W2_t, b2, x1, mod, OFF_G_MLP, out, M, DIM, MLP);
}